// Round 6
// baseline (834.910 us; speedup 1.0000x reference)
//
#include <hip/hip_runtime.h>

// Kalman filter fused step. D=1024, M=512, C=256, B=8192, fp32 in/out.
// Fast path: split-bf16 (hi+lo) MFMA GEMMs with global_load_lds staging
// (XOR-swizzled), fused split/transpose epilogues, Newton-Schulz inverse,
// and a fully fused state chain: state_n = [GF | GBc | Kg] @ [s; u; m].
// Fallback (ws too small): fp32 vector-ALU path with blocked GJ inverse.

static constexpr int Dd = 1024;
static constexpr int Mm = 512;
static constexpr int Cc = 256;
static constexpr int Bb = 8192;

typedef __bf16 bf16x8 __attribute__((ext_vector_type(8)));
typedef float f32x4 __attribute__((ext_vector_type(4)));
typedef unsigned short us;

// ---------------------------------------------------------------------------
// async global->LDS, 16 bytes per lane (literal size required)
// ---------------------------------------------------------------------------
__device__ __forceinline__ void gl16(const void* g, void* l)
{
    __builtin_amdgcn_global_load_lds(
        (const __attribute__((address_space(1))) void*)g,
        (__attribute__((address_space(3))) void*)l, 16, 0, 0);
}

__device__ __forceinline__ us bf16_hi(float v)
{
    return __builtin_bit_cast(us, (__bf16)v);
}
__device__ __forceinline__ us bf16_lo(float v)
{
    const __bf16 b = (__bf16)v;
    return __builtin_bit_cast(us, (__bf16)(v - (float)b));
}

// ===========================================================================
// Split-bf16 MFMA GEMM with fused epilogue.
//   C = addscale*ADD + sign * (A @ Bt^T)
//   A:[M,K] hi/lo (lda shorts); Bt:[N,K] hi/lo (ldb shorts). M,N%128, K%64.
// MODE bit0: write fp32 Cp (ldc). bit1: write split oh/ol [M,N] (ldo).
// bit2: write transposed split th/tl [N,M] (ldt).
// Staging: global_load_lds w=16 into linear LDS; bank-conflict-free via
// XOR swizzle (slot ^= row&7) applied to SOURCE address and ds_read only.
// ===========================================================================
template <int MODE, bool HAS_ADD>
__global__ __launch_bounds__(256) void gemm_bf16s(
    float* __restrict__ Cp, int ldc,
    us* __restrict__ oh, us* __restrict__ ol, int ldo,
    us* __restrict__ th, us* __restrict__ tl, int ldt,
    const us* __restrict__ Ahi, const us* __restrict__ Alo, int lda,
    const us* __restrict__ Bhi, const us* __restrict__ Blo, int ldb,
    const float* __restrict__ ADDp, int ldadd,
    int M, int N, int K, float sign, float addscale)
{
    __shared__ __align__(16) us lds[4][128][64];   // Ahi,Alo,Bhi,Blo tiles

    const int tid  = threadIdx.x;
    const int wave = tid >> 6, lane = tid & 63;
    const int l15  = lane & 15, lk = lane >> 4;
    const int wr   = (wave >> 1) * 64, wc = (wave & 1) * 64;
    const int row0 = blockIdx.y * 128, col0 = blockIdx.x * 128;

    // per-thread staging geometry (constant across K)
    int offA[4], offB[4];
#pragma unroll
    for (int j = 0; j < 4; ++j) {
        const int id  = j * 256 + tid;     // 0..1023 16B-slots
        const int r   = id >> 3;           // tile row 0..127
        const int c16 = id & 7;            // 16B slot within 128B row
        const int csw = c16 ^ (r & 7);     // pre-swizzled source slot
        offA[j] = (row0 + r) * lda * 2 + csw * 16;
        offB[j] = (col0 + r) * ldb * 2 + csw * 16;
    }
    const char* pAh = (const char*)Ahi;
    const char* pAl = (const char*)Alo;
    const char* pBh = (const char*)Bhi;
    const char* pBl = (const char*)Blo;
    char* dA0 = (char*)&lds[0][0][0];
    char* dA1 = (char*)&lds[1][0][0];
    char* dB0 = (char*)&lds[2][0][0];
    char* dB1 = (char*)&lds[3][0][0];

    const int sl0 = (0 * 4 + lk) ^ (l15 & 7);   // ks=0 read slot
    const int sl1 = (1 * 4 + lk) ^ (l15 & 7);   // ks=1 read slot

    f32x4 acc[4][4] = {};

    for (int k0 = 0; k0 < K; k0 += 64) {
        const int k2 = k0 * 2;
#pragma unroll
        for (int j = 0; j < 4; ++j) {
            const int d = (j * 256 + tid) * 16;
            gl16(pAh + offA[j] + k2, dA0 + d);
            gl16(pAl + offA[j] + k2, dA1 + d);
            gl16(pBh + offB[j] + k2, dB0 + d);
            gl16(pBl + offB[j] + k2, dB1 + d);
        }
        __syncthreads();   // compiler emits vmcnt(0) drain before barrier

#pragma unroll
        for (int ks = 0; ks < 2; ++ks) {
            const int sl = ks ? sl1 : sl0;
            bf16x8 ah[4], al[4], bh[4], bl[4];
#pragma unroll
            for (int mi = 0; mi < 4; ++mi) {
                ah[mi] = *reinterpret_cast<const bf16x8*>(&lds[0][wr + mi * 16 + l15][sl * 8]);
                al[mi] = *reinterpret_cast<const bf16x8*>(&lds[1][wr + mi * 16 + l15][sl * 8]);
                bh[mi] = *reinterpret_cast<const bf16x8*>(&lds[2][wc + mi * 16 + l15][sl * 8]);
                bl[mi] = *reinterpret_cast<const bf16x8*>(&lds[3][wc + mi * 16 + l15][sl * 8]);
            }
#pragma unroll
            for (int mi = 0; mi < 4; ++mi)
#pragma unroll
                for (int nj = 0; nj < 4; ++nj) {
                    acc[mi][nj] = __builtin_amdgcn_mfma_f32_16x16x32_bf16(ah[mi], bh[nj], acc[mi][nj], 0, 0, 0);
                    acc[mi][nj] = __builtin_amdgcn_mfma_f32_16x16x32_bf16(ah[mi], bl[nj], acc[mi][nj], 0, 0, 0);
                    acc[mi][nj] = __builtin_amdgcn_mfma_f32_16x16x32_bf16(al[mi], bh[nj], acc[mi][nj], 0, 0, 0);
                }
        }
        __syncthreads();
    }

#pragma unroll
    for (int mi = 0; mi < 4; ++mi)
#pragma unroll
        for (int nj = 0; nj < 4; ++nj)
#pragma unroll
            for (int rr = 0; rr < 4; ++rr) {
                const int gr = row0 + wr + mi * 16 + lk * 4 + rr;
                const int gc = col0 + wc + nj * 16 + l15;
                float v = sign * acc[mi][nj][rr];
                if (HAS_ADD) v = fmaf(addscale, ADDp[(size_t)gr * ldadd + gc], v);
                if constexpr (MODE & 1)
                    Cp[(size_t)gr * ldc + gc] = v;
                if constexpr (MODE & 2) {
                    oh[(size_t)gr * ldo + gc] = bf16_hi(v);
                    ol[(size_t)gr * ldo + gc] = bf16_lo(v);
                }
                if constexpr (MODE & 4) {
                    th[(size_t)gc * ldt + gr] = bf16_hi(v);
                    tl[(size_t)gc * ldt + gr] = bf16_lo(v);
                }
            }
}

// ===========================================================================
// fp32 [R,C] (ldi) -> bf16 hi/lo [R,C] (ldo). C%4==0.
// ===========================================================================
__global__ void cvt_split_kernel(const float* __restrict__ in, int ldi,
                                 us* __restrict__ oh, us* __restrict__ ol, int ldo,
                                 int R, int Cq)
{
    const int total = R * Cq;
    for (int idx = blockIdx.x * blockDim.x + threadIdx.x; idx < total;
         idx += gridDim.x * blockDim.x) {
        const int r  = idx / Cq;
        const int c  = (idx - r * Cq) * 4;
        const float4 v = *reinterpret_cast<const float4*>(in + (size_t)r * ldi + c);
        const float vv[4] = {v.x, v.y, v.z, v.w};
        ushort4 h, l;
        unsigned short hs[4], ls[4];
#pragma unroll
        for (int j = 0; j < 4; ++j) { hs[j] = bf16_hi(vv[j]); ls[j] = bf16_lo(vv[j]); }
        h.x = hs[0]; h.y = hs[1]; h.z = hs[2]; h.w = hs[3];
        l.x = ls[0]; l.y = ls[1]; l.z = ls[2]; l.w = ls[3];
        *reinterpret_cast<ushort4*>(oh + (size_t)r * ldo + c) = h;
        *reinterpret_cast<ushort4*>(ol + (size_t)r * ldo + c) = l;
    }
}

// ===========================================================================
// fp32 [R,C] (ldi) -> transposed bf16 hi/lo [C,R] (ldo). R,C %32==0.
// ===========================================================================
__global__ __launch_bounds__(256) void cvt_split_t_kernel(
    const float* __restrict__ in, int ldi,
    us* __restrict__ oh, us* __restrict__ ol, int ldo,
    int R, int C)
{
    __shared__ float Ts[32][33];
    const int tx = threadIdx.x & 31, ty = threadIdx.x >> 5;
    const int c0 = blockIdx.x * 32, r0 = blockIdx.y * 32;
#pragma unroll
    for (int i = 0; i < 4; ++i) {
        const int r = ty + i * 8;
        Ts[r][tx] = in[(size_t)(r0 + r) * ldi + c0 + tx];
    }
    __syncthreads();
#pragma unroll
    for (int i = 0; i < 4; ++i) {
        const int c = ty + i * 8;
        const float v = Ts[tx][c];
        const size_t o = (size_t)(c0 + c) * ldo + r0 + tx;
        oh[o] = bf16_hi(v);
        ol[o] = bf16_lo(v);
    }
}

// ===========================================================================
// fp32 [R,C] -> BOTH normal hi/lo (ldn) and transposed hi/lo (ldt)
// ===========================================================================
__global__ __launch_bounds__(256) void cvt_split_both_kernel(
    const float* __restrict__ in, int ldi,
    us* __restrict__ oh, us* __restrict__ ol, int ldn,
    us* __restrict__ th, us* __restrict__ tl, int ldt,
    int R, int C)
{
    __shared__ float Ts[32][33];
    const int tx = threadIdx.x & 31, ty = threadIdx.x >> 5;
    const int c0 = blockIdx.x * 32, r0 = blockIdx.y * 32;
#pragma unroll
    for (int i = 0; i < 4; ++i) {
        const int r = ty + i * 8;
        const float v = in[(size_t)(r0 + r) * ldi + c0 + tx];
        Ts[r][tx] = v;
        const size_t o = (size_t)(r0 + r) * ldn + c0 + tx;
        oh[o] = bf16_hi(v);
        ol[o] = bf16_lo(v);
    }
    __syncthreads();
#pragma unroll
    for (int i = 0; i < 4; ++i) {
        const int c = ty + i * 8;
        const float v = Ts[tx][c];
        const size_t o = (size_t)(c0 + c) * ldt + r0 + tx;
        th[o] = bf16_hi(v);
        tl[o] = bf16_lo(v);
    }
}

// ===========================================================================
// Newton-Schulz helpers
// ===========================================================================
__global__ __launch_bounds__(256) void rowabsmax_kernel(
    const float* __restrict__ S, int lds_, unsigned int* __restrict__ out)
{
    __shared__ float wsum[4];
    const int r = blockIdx.x;
    float s = 0.f;
    for (int c = threadIdx.x; c < 512; c += 256) s += fabsf(S[(size_t)r * lds_ + c]);
#pragma unroll
    for (int o = 32; o > 0; o >>= 1) s += __shfl_down(s, o, 64);
    if ((threadIdx.x & 63) == 0) wsum[threadIdx.x >> 6] = s;
    __syncthreads();
    if (threadIdx.x == 0) {
        const float t = wsum[0] + wsum[1] + wsum[2] + wsum[3];
        atomicMax(out, __float_as_uint(t));
    }
}

__global__ void initx1_kernel(const float* __restrict__ S, int lds_,
                              const unsigned int* __restrict__ cmax,
                              float* __restrict__ X)
{
    const int idx = blockIdx.x * 256 + threadIdx.x;  // 512*512
    const float a = 1.f / __uint_as_float(*cmax);
    const int r = idx >> 9, c = idx & 511;
    X[idx] = 2.f * a * ((r == c) ? 1.f : 0.f) - a * a * S[(size_t)r * lds_ + c];
}

// ===========================================================================
// fp32 fallback path (only used if ws tiny)
// ===========================================================================
template <bool TRANSB>
__global__ __launch_bounds__(256) void gemm_f32(
    float* __restrict__ Cp, int ldc,
    const float* __restrict__ Ap, int lda,
    const float* __restrict__ Bp, int ldb,
    const float* __restrict__ ADDp, int ldadd,
    int M, int N, int K, float sign)
{
    __shared__ float As[16][132];
    __shared__ float Bs[16][132];
    const int tid  = threadIdx.x;
    const int row0 = blockIdx.y * 128;
    const int col0 = blockIdx.x * 128;
    const int tr   = tid >> 4;
    const int tc   = tid & 15;
    float acc[8][8];
#pragma unroll
    for (int i = 0; i < 8; ++i)
#pragma unroll
        for (int j = 0; j < 8; ++j) acc[i][j] = 0.f;

    for (int k0 = 0; k0 < K; k0 += 16) {
#pragma unroll
        for (int l = 0; l < 2; ++l) {
            const int f = tid + l * 256;
            const int r = f >> 2;
            const int kq = (f & 3) << 2;
            const int grow = row0 + r;
            float4 v = make_float4(0.f, 0.f, 0.f, 0.f);
            if (grow < M)
                v = *reinterpret_cast<const float4*>(Ap + (size_t)grow * lda + k0 + kq);
            As[kq + 0][r] = v.x; As[kq + 1][r] = v.y;
            As[kq + 2][r] = v.z; As[kq + 3][r] = v.w;
        }
        if (!TRANSB) {
#pragma unroll
            for (int l = 0; l < 2; ++l) {
                const int f = tid + l * 256;
                const int kk = f >> 5;
                const int cq = (f & 31) << 2;
                const int gcol = col0 + cq;
                float4 v = make_float4(0.f, 0.f, 0.f, 0.f);
                if (gcol + 3 < N)
                    v = *reinterpret_cast<const float4*>(Bp + (size_t)(k0 + kk) * ldb + gcol);
                *reinterpret_cast<float4*>(&Bs[kk][cq]) = v;
            }
        } else {
#pragma unroll
            for (int l = 0; l < 2; ++l) {
                const int f = tid + l * 256;
                const int n = f >> 2;
                const int kq = (f & 3) << 2;
                const int gcol = col0 + n;
                float4 v = make_float4(0.f, 0.f, 0.f, 0.f);
                if (gcol < N)
                    v = *reinterpret_cast<const float4*>(Bp + (size_t)gcol * ldb + k0 + kq);
                Bs[kq + 0][n] = v.x; Bs[kq + 1][n] = v.y;
                Bs[kq + 2][n] = v.z; Bs[kq + 3][n] = v.w;
            }
        }
        __syncthreads();
#pragma unroll
        for (int kk = 0; kk < 16; ++kk) {
            const float4 a0 = *reinterpret_cast<const float4*>(&As[kk][tr * 8]);
            const float4 a1 = *reinterpret_cast<const float4*>(&As[kk][tr * 8 + 4]);
            const float4 b0 = *reinterpret_cast<const float4*>(&Bs[kk][tc * 8]);
            const float4 b1 = *reinterpret_cast<const float4*>(&Bs[kk][tc * 8 + 4]);
            const float a_frag[8] = {a0.x, a0.y, a0.z, a0.w, a1.x, a1.y, a1.z, a1.w};
            const float b_frag[8] = {b0.x, b0.y, b0.z, b0.w, b1.x, b1.y, b1.z, b1.w};
#pragma unroll
            for (int i = 0; i < 8; ++i)
#pragma unroll
                for (int j = 0; j < 8; ++j)
                    acc[i][j] = fmaf(a_frag[i], b_frag[j], acc[i][j]);
        }
        __syncthreads();
    }
#pragma unroll
    for (int i = 0; i < 8; ++i) {
        const int grow = row0 + tr * 8 + i;
        if (grow >= M) continue;
        const int gcol = col0 + tc * 8;
#pragma unroll
        for (int j = 0; j < 8; ++j) {
            const int gc = gcol + j;
            if (gc < N) {
                const float add = ADDp ? ADDp[(size_t)grow * ldadd + gc] : 0.f;
                Cp[(size_t)grow * ldc + gc] = fmaf(sign, acc[i][j], add);
            }
        }
    }
}

__global__ __launch_bounds__(256) void inv64_kernel(
    const float* __restrict__ W, int ldw, int kb, float* __restrict__ Dinv)
{
    __shared__ float T[64][129];
    __shared__ float multcol[64];
    const int tid = threadIdx.x;
    for (int idx = tid; idx < 64 * 64; idx += 256) {
        const int r = idx >> 6, c = idx & 63;
        T[r][c]      = W[(size_t)(kb * 64 + r) * ldw + kb * 64 + c];
        T[r][64 + c] = (r == c) ? 1.f : 0.f;
    }
    __syncthreads();
    for (int p = 0; p < 64; ++p) {
        const float rp = 1.f / T[p][p];
        __syncthreads();
        if (tid < 128) T[p][tid] *= rp;
        if (tid >= 128 && tid < 192) multcol[tid - 128] = T[tid - 128][p];
        __syncthreads();
        for (int idx = tid; idx < 64 * 128; idx += 256) {
            const int r = idx >> 7, c = idx & 127;
            if (r != p) T[r][c] = fmaf(-multcol[r], T[p][c], T[r][c]);
        }
        __syncthreads();
    }
    for (int idx = tid; idx < 64 * 64; idx += 256) {
        const int r = idx >> 6, c = idx & 63;
        Dinv[idx] = T[r][64 + c];
    }
}

__global__ void init_eye_kernel(float* __restrict__ W)
{
    const int idx = blockIdx.x * 256 + threadIdx.x;
    if (idx < 512 * 512) {
        const int r = idx >> 9, c = idx & 511;
        W[(size_t)r * 1024 + 512 + c] = (r == c) ? 1.f : 0.f;
    }
}

__global__ void multcopy_kernel(const float* __restrict__ W, float* __restrict__ Mbuf, int kb)
{
    const int idx = blockIdx.x * 256 + threadIdx.x;
    if (idx < 512 * 64) {
        const int r = idx >> 6, c = idx & 63;
        const float v = W[(size_t)r * 1024 + kb * 64 + c];
        Mbuf[idx] = ((r >> 6) == kb) ? 0.f : v;
    }
}

static void run_fp32_path(void* const* d_in, void* d_out, void* d_ws, hipStream_t stream)
{
    const float* state   = (const float*)d_in[0];
    const float* cov     = (const float*)d_in[1];
    const float* meas    = (const float*)d_in[2];
    const float* control = (const float*)d_in[3];
    const float* F       = (const float*)d_in[4];
    const float* Q       = (const float*)d_in[5];
    const float* Bc      = (const float*)d_in[6];
    const float* H       = (const float*)d_in[7];
    const float* R       = (const float*)d_in[8];

    float* out_state = (float*)d_out;
    float* out_cov   = out_state + (size_t)Dd * Bb;
    float* T1        = out_cov;

    float* ws    = (float*)d_ws;
    float* cov_p = ws;  ws += (size_t)Dd * Dd;
    float* HCP   = ws;  ws += (size_t)Mm * Dd;
    float* W     = ws;  ws += (size_t)Mm * 1024;
    float* Mbuf  = ws;  ws += (size_t)Mm * 64;
    float* Dinv  = ws;  ws += 64 * 64;
    float* Kg    = ws;  ws += (size_t)Dd * Mm;
    float* KHI   = ws;  ws += (size_t)Dd * Dd;

    const dim3 blk(256);
    gemm_f32<false><<<dim3(Dd / 128, Dd / 128), blk, 0, stream>>>(
        T1, Dd, F, Dd, cov, Dd, nullptr, 0, Dd, Dd, Dd, 1.f);
    gemm_f32<true><<<dim3(Dd / 128, Dd / 128), blk, 0, stream>>>(
        cov_p, Dd, T1, Dd, F, Dd, Q, Dd, Dd, Dd, Dd, 1.f);
    gemm_f32<false><<<dim3(Dd / 128, Mm / 128), blk, 0, stream>>>(
        HCP, Dd, H, Dd, cov_p, Dd, nullptr, 0, Mm, Dd, Dd, 1.f);
    gemm_f32<true><<<dim3(Mm / 128, Mm / 128), blk, 0, stream>>>(
        W, 1024, HCP, Dd, H, Dd, R, Mm, Mm, Mm, Dd, 1.f);
    init_eye_kernel<<<dim3((512 * 512) / 256), blk, 0, stream>>>(W);
    for (int kb = 0; kb < 8; ++kb) {
        inv64_kernel<<<dim3(1), blk, 0, stream>>>(W, 1024, kb, Dinv);
        gemm_f32<false><<<dim3(1024 / 128, 1), blk, 0, stream>>>(
            W + (size_t)kb * 64 * 1024, 1024, Dinv, 64,
            W + (size_t)kb * 64 * 1024, 1024, nullptr, 0, 64, 1024, 64, 1.f);
        multcopy_kernel<<<dim3((512 * 64) / 256), blk, 0, stream>>>(W, Mbuf, kb);
        gemm_f32<false><<<dim3(1024 / 128, 512 / 128), blk, 0, stream>>>(
            W, 1024, Mbuf, 64, W + (size_t)kb * 64 * 1024, 1024,
            W, 1024, 512, 1024, 64, -1.f);
    }
    float* Sinv = W + 512;
    gemm_f32<true><<<dim3(Mm / 128, Dd / 128), blk, 0, stream>>>(
        HCP, Mm, cov_p, Dd, H, Dd, nullptr, 0, Dd, Mm, Dd, 1.f);
    gemm_f32<false><<<dim3(Mm / 128, Dd / 128), blk, 0, stream>>>(
        Kg, Mm, HCP, Mm, Sinv, 1024, nullptr, 0, Dd, Mm, Mm, 1.f);
    gemm_f32<false><<<dim3(Dd / 128, Dd / 128), blk, 0, stream>>>(
        KHI, Dd, Kg, Mm, H, Dd, nullptr, 0, Dd, Dd, Mm, 1.f);
    gemm_f32<false><<<dim3(Dd / 128, Dd / 128), blk, 0, stream>>>(
        out_cov, Dd, KHI, Dd, cov_p, Dd, cov_p, Dd, Dd, Dd, Dd, -1.f);
    gemm_f32<false><<<dim3(Bb / 128, Dd / 128), blk, 0, stream>>>(
        out_state, Bb, F, Dd, state, Bb, nullptr, 0, Dd, Bb, Dd, 1.f);
    gemm_f32<false><<<dim3(Bb / 128, Dd / 128), blk, 0, stream>>>(
        out_state, Bb, Bc, Cc, control, Bb, out_state, Bb, Dd, Bb, Cc, 1.f);
    for (int b0 = 0; b0 < Bb; b0 += 2048) {
        float* innov_c = KHI;
        gemm_f32<false><<<dim3(2048 / 128, Mm / 128), blk, 0, stream>>>(
            innov_c, 2048, H, Dd, out_state + b0, Bb, meas + b0, Bb,
            Mm, 2048, Dd, -1.f);
        gemm_f32<false><<<dim3(2048 / 128, Dd / 128), blk, 0, stream>>>(
            out_state + b0, Bb, Kg, Mm, innov_c, 2048, out_state + b0, Bb,
            Dd, 2048, Mm, 1.f);
    }
}

// ===========================================================================
// launch
// ===========================================================================
extern "C" void kernel_launch(void* const* d_in, const int* in_sizes, int n_in,
                              void* d_out, int out_size, void* d_ws, size_t ws_size,
                              hipStream_t stream)
{
    if (ws_size < 55000000ull) { run_fp32_path(d_in, d_out, d_ws, stream); return; }

    const float* state   = (const float*)d_in[0];
    const float* cov     = (const float*)d_in[1];   // symmetric
    const float* meas    = (const float*)d_in[2];
    const float* control = (const float*)d_in[3];
    const float* F       = (const float*)d_in[4];
    const float* Q       = (const float*)d_in[5];
    const float* Bc      = (const float*)d_in[6];
    const float* H       = (const float*)d_in[7];
    const float* R       = (const float*)d_in[8];

    float* out_state = (float*)d_out;
    float* out_cov   = out_state + (size_t)Dd * Bb;

    const int NC = (ws_size >= 75000000ull) ? 8192 : 4096;   // state-chain chunk

    // ---- arena ----
    size_t off = 0;
    auto alloc = [&](size_t bytes) {
        void* p = (char*)d_ws + off;
        off = (off + bytes + 255) & ~(size_t)255;
        return p;
    };
    // persistent (live through cov + state chains)
    us* F_h    = (us*)alloc(2097152);  us* F_l    = (us*)alloc(2097152);  // F [1024,1024] (A- & Bt-form)
    us* H_h    = (us*)alloc(1048576);  us* H_l    = (us*)alloc(1048576);  // H [512,1024]
    us* HT_h   = (us*)alloc(1048576);  us* HT_l   = (us*)alloc(1048576);  // H^T [1024,512]
    us* comb_h = (us*)alloc(3670016);  us* comb_l = (us*)alloc(3670016);  // [GF|GBc|Kg] [1024,1792]
    const size_t scr0 = off;   // scratch region start (cov-era, later overlaid)

    // cov-era scratch
    float* covp = (float*)alloc(4194304);                               // [1024,1024] fp32
    us* cA_h  = (us*)alloc(2097152);  us* cA_l  = (us*)alloc(2097152);  // cov, then covp A-form
    us* cT_h  = (us*)alloc(2097152);  us* cT_l  = (us*)alloc(2097152);  // covp T-form
    float* Sf = (float*)alloc(1048576);                                 // [512,512] fp32
    us* S_h   = (us*)alloc(524288);   us* S_l   = (us*)alloc(524288);
    us* t1_h  = (us*)alloc(2097152);  us* t1_l  = (us*)alloc(2097152);  // T1 A-form
    us* amh_h = (us*)alloc(1048576);  us* amh_l = (us*)alloc(1048576);  // HC then PHT
    us* KH_h  = (us*)alloc(2097152);  us* KH_l  = (us*)alloc(2097152);  // [1024,1024]
    us* FT_h  = (us*)alloc(2097152);  us* FT_l  = (us*)alloc(2097152);  // F^T [1024,1024]
    us* BcT_h = (us*)alloc(524288);   us* BcT_l = (us*)alloc(524288);   // Bc^T [256,1024]
    unsigned int* cmax = (unsigned int*)alloc(256);
    // Newton ping-pong
    float* Xf   = (float*)alloc(1048576);
    us* Xa_h = (us*)alloc(524288);  us* Xa_l = (us*)alloc(524288);
    us* Xt_h = (us*)alloc(524288);  us* Xt_l = (us*)alloc(524288);
    float* X2f  = (float*)alloc(1048576);
    us* X2a_h = (us*)alloc(524288); us* X2a_l = (us*)alloc(524288);
    us* X2t_h = (us*)alloc(524288); us* X2t_l = (us*)alloc(524288);
    us* Yt_h  = (us*)alloc(524288); us* Yt_l  = (us*)alloc(524288);

    // state-era scratch (OVERLAYS cov-era region; used only after cov chain)
    size_t soff = scr0;
    auto salloc = [&](size_t bytes) {
        void* p = (char*)d_ws + soff;
        soff = (soff + bytes + 255) & ~(size_t)255;
        return p;
    };
    us* btin_h = (us*)salloc((size_t)NC * 1792 * 2);   // [NC,1792] = [s;u;m]^T
    us* btin_l = (us*)salloc((size_t)NC * 1792 * 2);

    const dim3 blk(256);
    auto cvt = [&](const float* in, int ldi, us* oh, us* ol, int ldo, int Rr, int Cn) {
        const int total4 = Rr * (Cn / 4);
        const int grid = min(4096, (total4 + 255) / 256);
        cvt_split_kernel<<<dim3(grid), blk, 0, stream>>>(in, ldi, oh, ol, ldo, Rr, Cn / 4);
    };
    auto cvtT = [&](const float* in, int ldi, us* oh, us* ol, int ldo, int Rr, int Cn) {
        cvt_split_t_kernel<<<dim3(Cn / 32, Rr / 32), blk, 0, stream>>>(in, ldi, oh, ol, ldo, Rr, Cn);
    };

#define MM(MODE, Cp, ldc, oh, ol, ldo, th, tl, ldt, Ah, Al, lda, Bh, Bl, ldb, ADD, ldadd, M_, N_, K_, sg, as_)      \
    do {                                                                                                            \
        if ((ADD) != nullptr)                                                                                       \
            gemm_bf16s<MODE, true><<<dim3((N_) / 128, (M_) / 128), blk, 0, stream>>>(                               \
                Cp, ldc, oh, ol, ldo, th, tl, ldt, Ah, Al, lda, Bh, Bl, ldb, ADD, ldadd, M_, N_, K_, sg, as_);      \
        else                                                                                                        \
            gemm_bf16s<MODE, false><<<dim3((N_) / 128, (M_) / 128), blk, 0, stream>>>(                              \
                Cp, ldc, oh, ol, ldo, th, tl, ldt, Ah, Al, lda, Bh, Bl, ldb, nullptr, 0, M_, N_, K_, sg, as_);      \
    } while (0)

    // ---- input conversions ----
    cvt(F, 1024, F_h, F_l, 1024, 1024, 1024);        // F (A-form; also Bt-form for @F^T)
    cvtT(F, 1024, FT_h, FT_l, 1024, 1024, 1024);     // F^T (Bt-form for @F)
    cvtT(Bc, 256, BcT_h, BcT_l, 1024, 1024, 256);    // Bc^T [256,1024]
    cvt(cov, 1024, cA_h, cA_l, 1024, 1024, 1024);    // cov (symmetric) Bt-form
    cvt(H, 1024, H_h, H_l, 1024, 512, 1024);
    cvtT(H, 1024, HT_h, HT_l, 512, 512, 1024);

    // ---- covariance chain ----
    // T1 = F @ cov -> split only
    MM(2, (float*)nullptr, 0, t1_h, t1_l, 1024, (us*)nullptr, (us*)nullptr, 0,
       F_h, F_l, 1024, cA_h, cA_l, 1024, (const float*)nullptr, 0, 1024, 1024, 1024, 1.f, 1.f);
    // covp = T1 @ F^T + Q -> fp32 + A-form + T-form   (Bt = F row-major)
    MM(7, covp, 1024, cA_h, cA_l, 1024, cT_h, cT_l, 1024,
       t1_h, t1_l, 1024, F_h, F_l, 1024, Q, 1024, 1024, 1024, 1024, 1.f, 1.f);
    // HC = H @ covp -> split
    MM(2, (float*)nullptr, 0, amh_h, amh_l, 1024, (us*)nullptr, (us*)nullptr, 0,
       H_h, H_l, 1024, cT_h, cT_l, 1024, (const float*)nullptr, 0, 512, 1024, 1024, 1.f, 1.f);
    // S = HC @ H^T + R -> fp32 + split
    MM(3, Sf, 512, S_h, S_l, 512, (us*)nullptr, (us*)nullptr, 0,
       amh_h, amh_l, 1024, H_h, H_l, 1024, R, 512, 512, 512, 1024, 1.f, 1.f);

    // ---- Newton-Schulz inverse of S ----
    hipMemsetAsync(cmax, 0, 4, stream);
    rowabsmax_kernel<<<dim3(512), blk, 0, stream>>>(Sf, 512, cmax);
    initx1_kernel<<<dim3(1024), blk, 0, stream>>>(Sf, 512, cmax, Xf);
    cvt_split_both_kernel<<<dim3(16, 16), blk, 0, stream>>>(
        Xf, 512, Xa_h, Xa_l, 512, Xt_h, Xt_l, 512, 512, 512);
    for (int it = 0; it < 7; ++it) {
        // Yt = (S @ X)^T
        MM(4, (float*)nullptr, 0, (us*)nullptr, (us*)nullptr, 0, Yt_h, Yt_l, 512,
           S_h, S_l, 512, Xt_h, Xt_l, 512, (const float*)nullptr, 0, 512, 512, 512, 1.f, 1.f);
        // X2 = 2X - X@Y -> fp32 + A-form + T-form
        MM(7, X2f, 512, X2a_h, X2a_l, 512, X2t_h, X2t_l, 512,
           Xa_h, Xa_l, 512, Yt_h, Yt_l, 512, Xf, 512, 512, 512, 512, -1.f, 2.f);
        { float* t = Xf; Xf = X2f; X2f = t; }
        { us* t = Xa_h; Xa_h = X2a_h; X2a_h = t; }
        { us* t = Xa_l; Xa_l = X2a_l; X2a_l = t; }
        { us* t = Xt_h; Xt_h = X2t_h; X2t_h = t; }
        { us* t = Xt_l; Xt_l = X2t_l; X2t_l = t; }
    }
    // Sinv^T == final Xt

    // ---- gain + covariance update + state-operator precompute ----
    // PHT = covp @ H^T -> split (amh, ld512)
    MM(2, (float*)nullptr, 0, amh_h, amh_l, 512, (us*)nullptr, (us*)nullptr, 0,
       cA_h, cA_l, 1024, H_h, H_l, 1024, (const float*)nullptr, 0, 1024, 512, 1024, 1.f, 1.f);
    // Kg = PHT @ Sinv -> split, directly into comb cols [1280,1792)
    MM(2, (float*)nullptr, 0, comb_h + 1280, comb_l + 1280, 1792, (us*)nullptr, (us*)nullptr, 0,
       amh_h, amh_l, 512, Xt_h, Xt_l, 512, (const float*)nullptr, 0, 1024, 512, 512, 1.f, 1.f);
    // KH = Kg @ H -> split  (A = Kg inside comb, lda 1792)
    MM(2, (float*)nullptr, 0, KH_h, KH_l, 1024, (us*)nullptr, (us*)nullptr, 0,
       comb_h + 1280, comb_l + 1280, 1792, HT_h, HT_l, 512, (const float*)nullptr, 0,
       1024, 1024, 512, 1.f, 1.f);
    // cov_n = covp - KH @ covp -> fp32 out
    MM(1, out_cov, 1024, (us*)nullptr, (us*)nullptr, 0, (us*)nullptr, (us*)nullptr, 0,
       KH_h, KH_l, 1024, cT_h, cT_l, 1024, covp, 1024, 1024, 1024, 1024, -1.f, 1.f);
    // GF = F - KH @ F -> comb cols [0,1024)   (Bt = F^T so Bt^T = F)
    MM(2, (float*)nullptr, 0, comb_h, comb_l, 1792, (us*)nullptr, (us*)nullptr, 0,
       KH_h, KH_l, 1024, FT_h, FT_l, 1024, F, 1024, 1024, 1024, 1024, -1.f, 1.f);
    // GBc = Bc - KH @ Bc -> comb cols [1024,1280)
    MM(2, (float*)nullptr, 0, comb_h + 1024, comb_l + 1024, 1792, (us*)nullptr, (us*)nullptr, 0,
       KH_h, KH_l, 1024, BcT_h, BcT_l, 1024, Bc, 256, 1024, 256, 1024, -1.f, 1.f);

    // ---- fused state chain: state_n = [GF|GBc|Kg] @ [s;u;m] ----
    for (int b0 = 0; b0 < Bb; b0 += NC) {
        cvtT(state + b0, 8192, btin_h, btin_l, 1792, 1024, NC);
        cvtT(control + b0, 8192, btin_h + 1024, btin_l + 1024, 1792, 256, NC);
        cvtT(meas + b0, 8192, btin_h + 1280, btin_l + 1280, 1792, 512, NC);
        MM(1, out_state + b0, 8192, (us*)nullptr, (us*)nullptr, 0, (us*)nullptr, (us*)nullptr, 0,
           comb_h, comb_l, 1792, btin_h, btin_l, 1792, (const float*)nullptr, 0,
           1024, NC, 1792, 1.f, 1.f);
    }
#undef MM
}

// Round 7
// 491.982 us; speedup vs baseline: 1.6970x; 1.6970x over previous
//
#include <hip/hip_runtime.h>

// Kalman filter fused step. D=1024, M=512, C=256, B=8192, fp32 in/out.
// Fast path: split-bf16 (hi+lo) MFMA GEMMs (TILE128/TILE64), global_load_lds
// staging (XOR-swizzled), fused split/transpose epilogues, Newton-Schulz
// inverse (6 iters), fused state chain state_n=[GF|GBc|Kg]@[s;u;m], and
// batched conversion kernels (mega input cvt + fused state transpose).
// Fallback (ws too small): fp32 vector-ALU path with blocked GJ inverse.

static constexpr int Dd = 1024;
static constexpr int Mm = 512;
static constexpr int Cc = 256;
static constexpr int Bb = 8192;

typedef __bf16 bf16x8 __attribute__((ext_vector_type(8)));
typedef float f32x4 __attribute__((ext_vector_type(4)));
typedef unsigned short us;

__device__ __forceinline__ void gl16(const void* g, void* l)
{
    __builtin_amdgcn_global_load_lds(
        (const __attribute__((address_space(1))) void*)g,
        (__attribute__((address_space(3))) void*)l, 16, 0, 0);
}

__device__ __forceinline__ us bf16_hi(float v)
{
    return __builtin_bit_cast(us, (__bf16)v);
}
__device__ __forceinline__ us bf16_lo(float v)
{
    const __bf16 b = (__bf16)v;
    return __builtin_bit_cast(us, (__bf16)(v - (float)b));
}

// ===========================================================================
// Split-bf16 MFMA GEMM with fused epilogue.  C = addscale*ADD + sign*(A@Bt^T)
//   A:[M,K] hi/lo (lda shorts); Bt:[N,K] hi/lo (ldb shorts). M,N%TM, K%64.
// MODE bit0: fp32 Cp (ldc). bit1: split oh/ol [M,N] (ldo). bit2: transposed
// split th/tl [N,M] (ldt).
// TM = tile edge (128 or 64). 4 waves, each owns (TM/2)x(TM/2).
// Staging: global_load_lds w=16, linear LDS dest, XOR swizzle (slot^=row&7)
// applied to SOURCE address and ds_read only (both-sides rule).
// ===========================================================================
template <int MODE, bool HAS_ADD, int TM>
__global__ __launch_bounds__(256) void gemm_bf16s(
    float* __restrict__ Cp, int ldc,
    us* __restrict__ oh, us* __restrict__ ol, int ldo,
    us* __restrict__ th, us* __restrict__ tl, int ldt,
    const us* __restrict__ Ahi, const us* __restrict__ Alo, int lda,
    const us* __restrict__ Bhi, const us* __restrict__ Blo, int ldb,
    const float* __restrict__ ADDp, int ldadd,
    int M, int N, int K, float sign, float addscale)
{
    constexpr int WT = TM / 2;    // per-wave tile edge
    constexpr int MT = WT / 16;   // 16x16 mfma tiles per wave dim
    constexpr int JS = TM / 32;   // staging iters (16B slots/thread/array)
    __shared__ __align__(16) us lds[4][TM][64];   // Ahi,Alo,Bhi,Blo

    const int tid  = threadIdx.x;
    const int wave = tid >> 6, lane = tid & 63;
    const int l15  = lane & 15, lk = lane >> 4;
    const int wr   = (wave >> 1) * WT, wc = (wave & 1) * WT;
    const int row0 = blockIdx.y * TM, col0 = blockIdx.x * TM;

    int offA[JS], offB[JS];
#pragma unroll
    for (int j = 0; j < JS; ++j) {
        const int id  = j * 256 + tid;     // 16B slot id
        const int r   = id >> 3;           // tile row
        const int c16 = id & 7;            // slot in 128B row
        const int csw = c16 ^ (r & 7);     // pre-swizzled source slot
        offA[j] = (row0 + r) * lda * 2 + csw * 16;
        offB[j] = (col0 + r) * ldb * 2 + csw * 16;
    }
    const char* pAh = (const char*)Ahi;
    const char* pAl = (const char*)Alo;
    const char* pBh = (const char*)Bhi;
    const char* pBl = (const char*)Blo;
    char* dA0 = (char*)&lds[0][0][0];
    char* dA1 = (char*)&lds[1][0][0];
    char* dB0 = (char*)&lds[2][0][0];
    char* dB1 = (char*)&lds[3][0][0];

    const int sl0 = (0 * 4 + lk) ^ (l15 & 7);
    const int sl1 = (1 * 4 + lk) ^ (l15 & 7);

    f32x4 acc[MT][MT] = {};

    for (int k0 = 0; k0 < K; k0 += 64) {
        const int k2 = k0 * 2;
#pragma unroll
        for (int j = 0; j < JS; ++j) {
            const int d = (j * 256 + tid) * 16;
            gl16(pAh + offA[j] + k2, dA0 + d);
            gl16(pAl + offA[j] + k2, dA1 + d);
            gl16(pBh + offB[j] + k2, dB0 + d);
            gl16(pBl + offB[j] + k2, dB1 + d);
        }
        __syncthreads();   // vmcnt(0) drain emitted by compiler

#pragma unroll
        for (int ks = 0; ks < 2; ++ks) {
            const int sl = ks ? sl1 : sl0;
            bf16x8 ah[MT], al[MT], bh[MT], bl[MT];
#pragma unroll
            for (int mi = 0; mi < MT; ++mi) {
                ah[mi] = *reinterpret_cast<const bf16x8*>(&lds[0][wr + mi * 16 + l15][sl * 8]);
                al[mi] = *reinterpret_cast<const bf16x8*>(&lds[1][wr + mi * 16 + l15][sl * 8]);
                bh[mi] = *reinterpret_cast<const bf16x8*>(&lds[2][wc + mi * 16 + l15][sl * 8]);
                bl[mi] = *reinterpret_cast<const bf16x8*>(&lds[3][wc + mi * 16 + l15][sl * 8]);
            }
#pragma unroll
            for (int mi = 0; mi < MT; ++mi)
#pragma unroll
                for (int nj = 0; nj < MT; ++nj) {
                    acc[mi][nj] = __builtin_amdgcn_mfma_f32_16x16x32_bf16(ah[mi], bh[nj], acc[mi][nj], 0, 0, 0);
                    acc[mi][nj] = __builtin_amdgcn_mfma_f32_16x16x32_bf16(ah[mi], bl[nj], acc[mi][nj], 0, 0, 0);
                    acc[mi][nj] = __builtin_amdgcn_mfma_f32_16x16x32_bf16(al[mi], bh[nj], acc[mi][nj], 0, 0, 0);
                }
        }
        __syncthreads();
    }

#pragma unroll
    for (int mi = 0; mi < MT; ++mi)
#pragma unroll
        for (int nj = 0; nj < MT; ++nj)
#pragma unroll
            for (int rr = 0; rr < 4; ++rr) {
                const int gr = row0 + wr + mi * 16 + lk * 4 + rr;
                const int gc = col0 + wc + nj * 16 + l15;
                float v = sign * acc[mi][nj][rr];
                if (HAS_ADD) v = fmaf(addscale, ADDp[(size_t)gr * ldadd + gc], v);
                if constexpr (MODE & 1)
                    Cp[(size_t)gr * ldc + gc] = v;
                if constexpr (MODE & 2) {
                    oh[(size_t)gr * ldo + gc] = bf16_hi(v);
                    ol[(size_t)gr * ldo + gc] = bf16_lo(v);
                }
                if constexpr (MODE & 4) {
                    th[(size_t)gc * ldt + gr] = bf16_hi(v);
                    tl[(size_t)gc * ldt + gr] = bf16_lo(v);
                }
            }
}

// ===========================================================================
// Mega input conversion: one launch converts F (A-form + T-into-FBcT + pack),
// Bc (T-into-FBcT + pack), cov (A-form), H (A-form). 32x32 tiles, job-decoded.
// Block ranges: [0,1024) F; [1024,1280) Bc; [1280,2304) cov; [2304,2816) H.
// ===========================================================================
__global__ __launch_bounds__(256) void megacvt_kernel(
    const float* __restrict__ F, const float* __restrict__ Bc,
    const float* __restrict__ cov, const float* __restrict__ H,
    us* __restrict__ F_h, us* __restrict__ F_l,
    float* __restrict__ pack,
    us* __restrict__ FBcT_h, us* __restrict__ FBcT_l,
    us* __restrict__ covB_h, us* __restrict__ covB_l,
    us* __restrict__ H_h, us* __restrict__ H_l)
{
    __shared__ float Ts[32][33];
    const int tx = threadIdx.x & 31, ty = threadIdx.x >> 5;
    const int jb = blockIdx.x;

    const float* src; int ldi, r0, c0;
    us *oh = nullptr, *ol = nullptr; int ldo = 0;
    float* pk = nullptr; int pc0 = 0;
    us *th = nullptr, *tl = nullptr; int tr0 = 0;

    if (jb < 1024) {                       // F [1024,1024]
        src = F; ldi = 1024; r0 = (jb >> 5) * 32; c0 = (jb & 31) * 32;
        oh = F_h; ol = F_l; ldo = 1024;
        pk = pack; pc0 = 0;
        th = FBcT_h; tl = FBcT_l; tr0 = 0;
    } else if (jb < 1280) {                // Bc [1024,256]
        const int t = jb - 1024;
        src = Bc; ldi = 256; r0 = (t >> 3) * 32; c0 = (t & 7) * 32;
        pk = pack; pc0 = 1024;
        th = FBcT_h; tl = FBcT_l; tr0 = 1024;
    } else if (jb < 2304) {                // cov [1024,1024] (symmetric)
        const int t = jb - 1280;
        src = cov; ldi = 1024; r0 = (t >> 5) * 32; c0 = (t & 31) * 32;
        oh = covB_h; ol = covB_l; ldo = 1024;
    } else {                               // H [512,1024]
        const int t = jb - 2304;
        src = H; ldi = 1024; r0 = (t >> 5) * 32; c0 = (t & 31) * 32;
        oh = H_h; ol = H_l; ldo = 1024;
    }

    const bool doT = (th != nullptr);
#pragma unroll
    for (int i = 0; i < 4; ++i) {
        const int r = ty + i * 8;
        const float v = src[(size_t)(r0 + r) * ldi + c0 + tx];
        if (doT) Ts[r][tx] = v;
        if (oh) {
            const size_t o = (size_t)(r0 + r) * ldo + c0 + tx;
            oh[o] = bf16_hi(v);
            ol[o] = bf16_lo(v);
        }
        if (pk) pk[(size_t)(r0 + r) * 1280 + pc0 + c0 + tx] = v;
    }
    if (doT) {
        __syncthreads();
#pragma unroll
        for (int i = 0; i < 4; ++i) {
            const int c = ty + i * 8;
            const float v = Ts[tx][c];
            const size_t o = (size_t)(tr0 + c0 + c) * 1024 + r0 + tx;
            th[o] = bf16_hi(v);
            tl[o] = bf16_lo(v);
        }
    }
}

// ===========================================================================
// Fused state-side transpose: [state|control|meas] chunk -> btin [NC,1792]
// hi/lo Bt-form. Tiles 32x32, job-decoded by block ranges.
// ===========================================================================
__global__ __launch_bounds__(256) void statecvt_kernel(
    const float* __restrict__ state, const float* __restrict__ control,
    const float* __restrict__ meas,
    us* __restrict__ btin_h, us* __restrict__ btin_l, int b0, int NC)
{
    __shared__ float Ts[32][33];
    const int tx = threadIdx.x & 31, ty = threadIdx.x >> 5;
    const int nct = NC / 32;
    const int jb  = blockIdx.x;

    const float* src; int R, cb, t;
    if (jb < nct * 32)      { src = state;   R = 1024; cb = 0;    t = jb; }
    else if (jb < nct * 40) { src = control; R = 256;  cb = 1024; t = jb - nct * 32; }
    else                    { src = meas;    R = 512;  cb = 1280; t = jb - nct * 40; }
    const int rt = R / 32;
    const int r0 = (t % rt) * 32, n0 = (t / rt) * 32;

#pragma unroll
    for (int i = 0; i < 4; ++i) {
        const int r = ty + i * 8;
        Ts[r][tx] = src[(size_t)(r0 + r) * 8192 + b0 + n0 + tx];
    }
    __syncthreads();
#pragma unroll
    for (int i = 0; i < 4; ++i) {
        const int c = ty + i * 8;
        const float v = Ts[tx][c];
        const size_t o = (size_t)(n0 + c) * 1792 + cb + r0 + tx;
        btin_h[o] = bf16_hi(v);
        btin_l[o] = bf16_lo(v);
    }
}

// ===========================================================================
// Newton-Schulz helpers
// ===========================================================================
// rowsum[r] = sum_c |S[r][c]|  (one block per row, no atomics)
__global__ __launch_bounds__(256) void rowabsmax_kernel(
    const float* __restrict__ S, float* __restrict__ rowsum)
{
    __shared__ float wsum[4];
    const int r = blockIdx.x;
    float s = 0.f;
    for (int c = threadIdx.x; c < 512; c += 256) s += fabsf(S[(size_t)r * 512 + c]);
#pragma unroll
    for (int o = 32; o > 0; o >>= 1) s += __shfl_down(s, o, 64);
    if ((threadIdx.x & 63) == 0) wsum[threadIdx.x >> 6] = s;
    __syncthreads();
    if (threadIdx.x == 0) rowsum[r] = wsum[0] + wsum[1] + wsum[2] + wsum[3];
}

// X1 = 2a*I - a^2*S, a = 1/max(rowsum); writes fp32 + A-form + T-form hi/lo.
__global__ __launch_bounds__(256) void initx1_both_kernel(
    const float* __restrict__ S, const float* __restrict__ rowsum,
    float* __restrict__ Xf,
    us* __restrict__ Xa_h, us* __restrict__ Xa_l,
    us* __restrict__ Xt_h, us* __restrict__ Xt_l)
{
    __shared__ float red[256];
    __shared__ float Ts[32][33];
    const int tid = threadIdx.x;
    red[tid] = fmaxf(rowsum[tid], rowsum[tid + 256]);
    __syncthreads();
    for (int o = 128; o > 0; o >>= 1) {
        if (tid < o) red[tid] = fmaxf(red[tid], red[tid + o]);
        __syncthreads();
    }
    const float a = 1.f / red[0];

    const int tx = tid & 31, ty = tid >> 5;
    const int c0 = (blockIdx.x & 15) * 32, r0 = (blockIdx.x >> 4) * 32;
#pragma unroll
    for (int i = 0; i < 4; ++i) {
        const int r = ty + i * 8;
        const float v = 2.f * a * ((r0 + r) == (c0 + tx) ? 1.f : 0.f)
                        - a * a * S[(size_t)(r0 + r) * 512 + c0 + tx];
        Ts[r][tx] = v;
        const size_t o = (size_t)(r0 + r) * 512 + c0 + tx;
        Xf[o]   = v;
        Xa_h[o] = bf16_hi(v);
        Xa_l[o] = bf16_lo(v);
    }
    __syncthreads();
#pragma unroll
    for (int i = 0; i < 4; ++i) {
        const int c = ty + i * 8;
        const float v = Ts[tx][c];
        const size_t o = (size_t)(c0 + c) * 512 + r0 + tx;
        Xt_h[o] = bf16_hi(v);
        Xt_l[o] = bf16_lo(v);
    }
}

// ===========================================================================
// fp32 fallback path (only used if ws tiny)
// ===========================================================================
template <bool TRANSB>
__global__ __launch_bounds__(256) void gemm_f32(
    float* __restrict__ Cp, int ldc,
    const float* __restrict__ Ap, int lda,
    const float* __restrict__ Bp, int ldb,
    const float* __restrict__ ADDp, int ldadd,
    int M, int N, int K, float sign)
{
    __shared__ float As[16][132];
    __shared__ float Bs[16][132];
    const int tid  = threadIdx.x;
    const int row0 = blockIdx.y * 128;
    const int col0 = blockIdx.x * 128;
    const int tr   = tid >> 4;
    const int tc   = tid & 15;
    float acc[8][8];
#pragma unroll
    for (int i = 0; i < 8; ++i)
#pragma unroll
        for (int j = 0; j < 8; ++j) acc[i][j] = 0.f;

    for (int k0 = 0; k0 < K; k0 += 16) {
#pragma unroll
        for (int l = 0; l < 2; ++l) {
            const int f = tid + l * 256;
            const int r = f >> 2;
            const int kq = (f & 3) << 2;
            const int grow = row0 + r;
            float4 v = make_float4(0.f, 0.f, 0.f, 0.f);
            if (grow < M)
                v = *reinterpret_cast<const float4*>(Ap + (size_t)grow * lda + k0 + kq);
            As[kq + 0][r] = v.x; As[kq + 1][r] = v.y;
            As[kq + 2][r] = v.z; As[kq + 3][r] = v.w;
        }
        if (!TRANSB) {
#pragma unroll
            for (int l = 0; l < 2; ++l) {
                const int f = tid + l * 256;
                const int kk = f >> 5;
                const int cq = (f & 31) << 2;
                const int gcol = col0 + cq;
                float4 v = make_float4(0.f, 0.f, 0.f, 0.f);
                if (gcol + 3 < N)
                    v = *reinterpret_cast<const float4*>(Bp + (size_t)(k0 + kk) * ldb + gcol);
                *reinterpret_cast<float4*>(&Bs[kk][cq]) = v;
            }
        } else {
#pragma unroll
            for (int l = 0; l < 2; ++l) {
                const int f = tid + l * 256;
                const int n = f >> 2;
                const int kq = (f & 3) << 2;
                const int gcol = col0 + n;
                float4 v = make_float4(0.f, 0.f, 0.f, 0.f);
                if (gcol < N)
                    v = *reinterpret_cast<const float4*>(Bp + (size_t)gcol * ldb + k0 + kq);
                Bs[kq + 0][n] = v.x; Bs[kq + 1][n] = v.y;
                Bs[kq + 2][n] = v.z; Bs[kq + 3][n] = v.w;
            }
        }
        __syncthreads();
#pragma unroll
        for (int kk = 0; kk < 16; ++kk) {
            const float4 a0 = *reinterpret_cast<const float4*>(&As[kk][tr * 8]);
            const float4 a1 = *reinterpret_cast<const float4*>(&As[kk][tr * 8 + 4]);
            const float4 b0 = *reinterpret_cast<const float4*>(&Bs[kk][tc * 8]);
            const float4 b1 = *reinterpret_cast<const float4*>(&Bs[kk][tc * 8 + 4]);
            const float a_frag[8] = {a0.x, a0.y, a0.z, a0.w, a1.x, a1.y, a1.z, a1.w};
            const float b_frag[8] = {b0.x, b0.y, b0.z, b0.w, b1.x, b1.y, b1.z, b1.w};
#pragma unroll
            for (int i = 0; i < 8; ++i)
#pragma unroll
                for (int j = 0; j < 8; ++j)
                    acc[i][j] = fmaf(a_frag[i], b_frag[j], acc[i][j]);
        }
        __syncthreads();
    }
#pragma unroll
    for (int i = 0; i < 8; ++i) {
        const int grow = row0 + tr * 8 + i;
        if (grow >= M) continue;
        const int gcol = col0 + tc * 8;
#pragma unroll
        for (int j = 0; j < 8; ++j) {
            const int gc = gcol + j;
            if (gc < N) {
                const float add = ADDp ? ADDp[(size_t)grow * ldadd + gc] : 0.f;
                Cp[(size_t)grow * ldc + gc] = fmaf(sign, acc[i][j], add);
            }
        }
    }
}

__global__ __launch_bounds__(256) void inv64_kernel(
    const float* __restrict__ W, int ldw, int kb, float* __restrict__ Dinv)
{
    __shared__ float T[64][129];
    __shared__ float multcol[64];
    const int tid = threadIdx.x;
    for (int idx = tid; idx < 64 * 64; idx += 256) {
        const int r = idx >> 6, c = idx & 63;
        T[r][c]      = W[(size_t)(kb * 64 + r) * ldw + kb * 64 + c];
        T[r][64 + c] = (r == c) ? 1.f : 0.f;
    }
    __syncthreads();
    for (int p = 0; p < 64; ++p) {
        const float rp = 1.f / T[p][p];
        __syncthreads();
        if (tid < 128) T[p][tid] *= rp;
        if (tid >= 128 && tid < 192) multcol[tid - 128] = T[tid - 128][p];
        __syncthreads();
        for (int idx = tid; idx < 64 * 128; idx += 256) {
            const int r = idx >> 7, c = idx & 127;
            if (r != p) T[r][c] = fmaf(-multcol[r], T[p][c], T[r][c]);
        }
        __syncthreads();
    }
    for (int idx = tid; idx < 64 * 64; idx += 256) {
        const int r = idx >> 6, c = idx & 63;
        Dinv[idx] = T[r][64 + c];
    }
}

__global__ void init_eye_kernel(float* __restrict__ W)
{
    const int idx = blockIdx.x * 256 + threadIdx.x;
    if (idx < 512 * 512) {
        const int r = idx >> 9, c = idx & 511;
        W[(size_t)r * 1024 + 512 + c] = (r == c) ? 1.f : 0.f;
    }
}

__global__ void multcopy_kernel(const float* __restrict__ W, float* __restrict__ Mbuf, int kb)
{
    const int idx = blockIdx.x * 256 + threadIdx.x;
    if (idx < 512 * 64) {
        const int r = idx >> 6, c = idx & 63;
        const float v = W[(size_t)r * 1024 + kb * 64 + c];
        Mbuf[idx] = ((r >> 6) == kb) ? 0.f : v;
    }
}

static void run_fp32_path(void* const* d_in, void* d_out, void* d_ws, hipStream_t stream)
{
    const float* state   = (const float*)d_in[0];
    const float* cov     = (const float*)d_in[1];
    const float* meas    = (const float*)d_in[2];
    const float* control = (const float*)d_in[3];
    const float* F       = (const float*)d_in[4];
    const float* Q       = (const float*)d_in[5];
    const float* Bc      = (const float*)d_in[6];
    const float* H       = (const float*)d_in[7];
    const float* R       = (const float*)d_in[8];

    float* out_state = (float*)d_out;
    float* out_cov   = out_state + (size_t)Dd * Bb;
    float* T1        = out_cov;

    float* ws    = (float*)d_ws;
    float* cov_p = ws;  ws += (size_t)Dd * Dd;
    float* HCP   = ws;  ws += (size_t)Mm * Dd;
    float* W     = ws;  ws += (size_t)Mm * 1024;
    float* Mbuf  = ws;  ws += (size_t)Mm * 64;
    float* Dinv  = ws;  ws += 64 * 64;
    float* Kg    = ws;  ws += (size_t)Dd * Mm;
    float* KHI   = ws;  ws += (size_t)Dd * Dd;

    const dim3 blk(256);
    gemm_f32<false><<<dim3(Dd / 128, Dd / 128), blk, 0, stream>>>(
        T1, Dd, F, Dd, cov, Dd, nullptr, 0, Dd, Dd, Dd, 1.f);
    gemm_f32<true><<<dim3(Dd / 128, Dd / 128), blk, 0, stream>>>(
        cov_p, Dd, T1, Dd, F, Dd, Q, Dd, Dd, Dd, Dd, 1.f);
    gemm_f32<false><<<dim3(Dd / 128, Mm / 128), blk, 0, stream>>>(
        HCP, Dd, H, Dd, cov_p, Dd, nullptr, 0, Mm, Dd, Dd, 1.f);
    gemm_f32<true><<<dim3(Mm / 128, Mm / 128), blk, 0, stream>>>(
        W, 1024, HCP, Dd, H, Dd, R, Mm, Mm, Mm, Dd, 1.f);
    init_eye_kernel<<<dim3((512 * 512) / 256), blk, 0, stream>>>(W);
    for (int kb = 0; kb < 8; ++kb) {
        inv64_kernel<<<dim3(1), blk, 0, stream>>>(W, 1024, kb, Dinv);
        gemm_f32<false><<<dim3(1024 / 128, 1), blk, 0, stream>>>(
            W + (size_t)kb * 64 * 1024, 1024, Dinv, 64,
            W + (size_t)kb * 64 * 1024, 1024, nullptr, 0, 64, 1024, 64, 1.f);
        multcopy_kernel<<<dim3((512 * 64) / 256), blk, 0, stream>>>(W, Mbuf, kb);
        gemm_f32<false><<<dim3(1024 / 128, 512 / 128), blk, 0, stream>>>(
            W, 1024, Mbuf, 64, W + (size_t)kb * 64 * 1024, 1024,
            W, 1024, 512, 1024, 64, -1.f);
    }
    float* Sinv = W + 512;
    gemm_f32<true><<<dim3(Mm / 128, Dd / 128), blk, 0, stream>>>(
        HCP, Mm, cov_p, Dd, H, Dd, nullptr, 0, Dd, Mm, Dd, 1.f);
    gemm_f32<false><<<dim3(Mm / 128, Dd / 128), blk, 0, stream>>>(
        Kg, Mm, HCP, Mm, Sinv, 1024, nullptr, 0, Dd, Mm, Mm, 1.f);
    gemm_f32<false><<<dim3(Dd / 128, Dd / 128), blk, 0, stream>>>(
        KHI, Dd, Kg, Mm, H, Dd, nullptr, 0, Dd, Dd, Mm, 1.f);
    gemm_f32<false><<<dim3(Dd / 128, Dd / 128), blk, 0, stream>>>(
        out_cov, Dd, KHI, Dd, cov_p, Dd, cov_p, Dd, Dd, Dd, Dd, -1.f);
    gemm_f32<false><<<dim3(Bb / 128, Dd / 128), blk, 0, stream>>>(
        out_state, Bb, F, Dd, state, Bb, nullptr, 0, Dd, Bb, Dd, 1.f);
    gemm_f32<false><<<dim3(Bb / 128, Dd / 128), blk, 0, stream>>>(
        out_state, Bb, Bc, Cc, control, Bb, out_state, Bb, Dd, Bb, Cc, 1.f);
    for (int b0 = 0; b0 < Bb; b0 += 2048) {
        float* innov_c = KHI;
        gemm_f32<false><<<dim3(2048 / 128, Mm / 128), blk, 0, stream>>>(
            innov_c, 2048, H, Dd, out_state + b0, Bb, meas + b0, Bb,
            Mm, 2048, Dd, -1.f);
        gemm_f32<false><<<dim3(2048 / 128, Dd / 128), blk, 0, stream>>>(
            out_state + b0, Bb, Kg, Mm, innov_c, 2048, out_state + b0, Bb,
            Dd, 2048, Mm, 1.f);
    }
}

// ===========================================================================
// launch
// ===========================================================================
extern "C" void kernel_launch(void* const* d_in, const int* in_sizes, int n_in,
                              void* d_out, int out_size, void* d_ws, size_t ws_size,
                              hipStream_t stream)
{
    if (ws_size < 55500000ull) { run_fp32_path(d_in, d_out, d_ws, stream); return; }

    const float* state   = (const float*)d_in[0];
    const float* cov     = (const float*)d_in[1];   // symmetric
    const float* meas    = (const float*)d_in[2];
    const float* control = (const float*)d_in[3];
    const float* F       = (const float*)d_in[4];
    const float* Q       = (const float*)d_in[5];
    const float* Bc      = (const float*)d_in[6];
    const float* H       = (const float*)d_in[7];
    const float* R       = (const float*)d_in[8];

    float* out_state = (float*)d_out;
    float* out_cov   = out_state + (size_t)Dd * Bb;

    const int NC = (ws_size >= 67000000ull) ? 8192 : 4096;

    // ---- arena ----
    size_t off = 0;
    auto alloc = [&](size_t bytes) {
        void* p = (char*)d_ws + off;
        off = (off + bytes + 255) & ~(size_t)255;
        return p;
    };
    // persistent through state era: comb only
    us* comb_h = (us*)alloc(3670016);  us* comb_l = (us*)alloc(3670016);  // [GF|GBc|Kg] [1024,1792]
    const size_t scr0 = off;

    // cov-era scratch (overlaid by btin later)
    us* F_h    = (us*)alloc(2097152);  us* F_l    = (us*)alloc(2097152);  // F [1024,1024]
    us* FBcT_h = (us*)alloc(2621440);  us* FBcT_l = (us*)alloc(2621440);  // [F|Bc]^T [1280,1024]
    float* FBcpack = (float*)alloc(5242880);                              // [F|Bc] fp32 [1024,1280]
    us* covB_h = (us*)alloc(2097152);  us* covB_l = (us*)alloc(2097152);  // cov Bt-form
    us* H_h    = (us*)alloc(1048576);  us* H_l    = (us*)alloc(1048576);  // H [512,1024]
    us* t1_h   = (us*)alloc(2097152);  us* t1_l   = (us*)alloc(2097152);  // T1 A-form; later HFBcT [1280,512]
    float* covp = (float*)alloc(4194304);                                 // fp32 [1024,1024]
    us* cpA_h  = (us*)alloc(2097152);  us* cpA_l  = (us*)alloc(2097152);  // covp A-form
    us* cpT_h  = (us*)alloc(2097152);  us* cpT_l  = (us*)alloc(2097152);  // covp T-form
    us* hcA_h  = (us*)alloc(1048576);  us* hcA_l  = (us*)alloc(1048576);  // HC A-form [512,1024]
    us* hcT_h  = (us*)alloc(1048576);  us* hcT_l  = (us*)alloc(1048576);  // HC T-form [1024,512]
    float* Sf  = (float*)alloc(1048576);                                  // S fp32 [512,512]
    us* S_h    = (us*)alloc(524288);   us* S_l    = (us*)alloc(524288);
    us* amh_h  = (us*)alloc(1048576);  us* amh_l  = (us*)alloc(1048576);  // PHT A-form [1024,512]
    float* rowsum = (float*)alloc(2048);
    float* Xf   = (float*)alloc(1048576);
    us* Xa_h = (us*)alloc(524288);  us* Xa_l = (us*)alloc(524288);
    us* Xt_h = (us*)alloc(524288);  us* Xt_l = (us*)alloc(524288);
    float* X2f  = (float*)alloc(1048576);
    us* X2a_h = (us*)alloc(524288); us* X2a_l = (us*)alloc(524288);
    us* X2t_h = (us*)alloc(524288); us* X2t_l = (us*)alloc(524288);
    us* Yt_h  = (us*)alloc(524288); us* Yt_l  = (us*)alloc(524288);

    // state-era scratch (overlays cov-era region)
    size_t soff = scr0;
    us* btin_h = (us*)((char*)d_ws + soff);  soff += ((size_t)NC * 1792 * 2 + 255) & ~(size_t)255;
    us* btin_l = (us*)((char*)d_ws + soff);

    const dim3 blk(256);

#define MM(MODE, TM, Cp, ldc, oh, ol, ldo, th, tl, ldt, Ah, Al, lda, Bh, Bl, ldb, ADD, ldadd, M_, N_, K_, sg, as_)  \
    do {                                                                                                            \
        if ((ADD) != nullptr)                                                                                       \
            gemm_bf16s<MODE, true, TM><<<dim3((N_) / (TM), (M_) / (TM)), blk, 0, stream>>>(                         \
                Cp, ldc, oh, ol, ldo, th, tl, ldt, Ah, Al, lda, Bh, Bl, ldb, ADD, ldadd, M_, N_, K_, sg, as_);      \
        else                                                                                                        \
            gemm_bf16s<MODE, false, TM><<<dim3((N_) / (TM), (M_) / (TM)), blk, 0, stream>>>(                        \
                Cp, ldc, oh, ol, ldo, th, tl, ldt, Ah, Al, lda, Bh, Bl, ldb, nullptr, 0, M_, N_, K_, sg, as_);      \
    } while (0)
#define NOF (float*)nullptr
#define NOS (us*)nullptr

    // ---- one-shot input conversion ----
    megacvt_kernel<<<dim3(2816), blk, 0, stream>>>(
        F, Bc, cov, H, F_h, F_l, FBcpack, FBcT_h, FBcT_l, covB_h, covB_l, H_h, H_l);

    // ---- covariance chain ----
    // T1 = F@cov (cov symmetric => Bt-form = cov)
    MM(2, 64, NOF, 0, t1_h, t1_l, 1024, NOS, NOS, 0,
       F_h, F_l, 1024, covB_h, covB_l, 1024, (const float*)nullptr, 0, 1024, 1024, 1024, 1.f, 1.f);
    // covp = T1@F^T + Q (Bt = F row-major)
    MM(7, 64, covp, 1024, cpA_h, cpA_l, 1024, cpT_h, cpT_l, 1024,
       t1_h, t1_l, 1024, F_h, F_l, 1024, Q, 1024, 1024, 1024, 1024, 1.f, 1.f);
    // HC = H@covp -> A-form (for S) + T-form (Bt for cov_n)
    MM(6, 64, NOF, 0, hcA_h, hcA_l, 1024, hcT_h, hcT_l, 512,
       H_h, H_l, 1024, cpT_h, cpT_l, 1024, (const float*)nullptr, 0, 512, 1024, 1024, 1.f, 1.f);
    // S = HC@H^T + R
    MM(3, 64, Sf, 512, S_h, S_l, 512, NOS, NOS, 0,
       hcA_h, hcA_l, 1024, H_h, H_l, 1024, R, 512, 512, 512, 1024, 1.f, 1.f);

    // ---- Newton-Schulz inverse of S (6 iterations after X1) ----
    rowabsmax_kernel<<<dim3(512), blk, 0, stream>>>(Sf, rowsum);
    initx1_both_kernel<<<dim3(256), blk, 0, stream>>>(Sf, rowsum, Xf, Xa_h, Xa_l, Xt_h, Xt_l);
    for (int it = 0; it < 6; ++it) {
        // Yt = (S@X)^T
        MM(4, 64, NOF, 0, NOS, NOS, 0, Yt_h, Yt_l, 512,
           S_h, S_l, 512, Xt_h, Xt_l, 512, (const float*)nullptr, 0, 512, 512, 512, 1.f, 1.f);
        // X2 = 2X - X@Y
        MM(7, 64, X2f, 512, X2a_h, X2a_l, 512, X2t_h, X2t_l, 512,
           Xa_h, Xa_l, 512, Yt_h, Yt_l, 512, Xf, 512, 512, 512, 512, -1.f, 2.f);
        { float* t = Xf; Xf = X2f; X2f = t; }
        { us* t = Xa_h; Xa_h = X2a_h; X2a_h = t; }
        { us* t = Xa_l; Xa_l = X2a_l; X2a_l = t; }
        { us* t = Xt_h; Xt_h = X2t_h; X2t_h = t; }
        { us* t = Xt_l; Xt_l = X2t_l; X2t_l = t; }
    }
    // Sinv^T == final Xt

    // ---- gain, covariance update, state-operator precompute ----
    // PHT = covp@H^T
    MM(2, 64, NOF, 0, amh_h, amh_l, 512, NOS, NOS, 0,
       cpA_h, cpA_l, 1024, H_h, H_l, 1024, (const float*)nullptr, 0, 1024, 512, 1024, 1.f, 1.f);
    // Kg = PHT@Sinv -> comb cols [1280,1792)
    MM(2, 64, NOF, 0, comb_h + 1280, comb_l + 1280, 1792, NOS, NOS, 0,
       amh_h, amh_l, 512, Xt_h, Xt_l, 512, (const float*)nullptr, 0, 1024, 512, 512, 1.f, 1.f);
    // HFBc = H@[F|Bc] -> T-form into t1 (HFBcT [1280,512])
    MM(4, 64, NOF, 0, NOS, NOS, 0, t1_h, t1_l, 512,
       H_h, H_l, 1024, FBcT_h, FBcT_l, 1024, (const float*)nullptr, 0, 512, 1280, 1024, 1.f, 1.f);
    // [GF|GBc] = [F|Bc] - Kg@HFBc -> comb cols [0,1280)
    MM(2, 64, NOF, 0, comb_h, comb_l, 1792, NOS, NOS, 0,
       comb_h + 1280, comb_l + 1280, 1792, t1_h, t1_l, 512, FBcpack, 1280, 1024, 1280, 512, -1.f, 1.f);
    // cov_n = covp - Kg@HC
    MM(1, 64, out_cov, 1024, NOS, NOS, 0, NOS, NOS, 0,
       comb_h + 1280, comb_l + 1280, 1792, hcT_h, hcT_l, 512, covp, 1024, 1024, 1024, 512, -1.f, 1.f);

    // ---- fused state chain: state_n = [GF|GBc|Kg] @ [s;u;m] ----
    for (int b0 = 0; b0 < Bb; b0 += NC) {
        statecvt_kernel<<<dim3((NC / 32) * 56), blk, 0, stream>>>(
            state, control, meas, btin_h, btin_l, b0, NC);
        MM(1, 128, out_state + b0, 8192, NOS, NOS, 0, NOS, NOS, 0,
           comb_h, comb_l, 1792, btin_h, btin_l, 1792, (const float*)nullptr, 0,
           1024, NC, 1792, 1.f, 1.f);
    }
#undef MM
#undef NOF
#undef NOS
}